// Round 10
// baseline (137.108 us; speedup 1.0000x reference)
//
#include <hip/hip_runtime.h>
#include <hip/hip_bf16.h>
#include <math.h>

#define NN 4096
#define HH 4
#define LOG2E 1.44269504f

typedef _Float16 h2 __attribute__((ext_vector_type(2)));
typedef _Float16 h4 __attribute__((ext_vector_type(4)));
typedef _Float16 h8 __attribute__((ext_vector_type(8)));
typedef float f4 __attribute__((ext_vector_type(4)));

static __device__ __forceinline__ h2 cvt2(float a, float b) {
  return __builtin_bit_cast(h2, __builtin_amdgcn_cvt_pkrtz(a, b));
}

#if __has_builtin(__builtin_amdgcn_exp2f)
#define EXP2(x) __builtin_amdgcn_exp2f(x)
#else
#define EXP2(x) exp2f(x)
#endif

// ---------------- K1: ht GEMM -> vfrag + posfrag + src/tgt (pre-scaled) ----------------
// vfrag element (h, jt, lane, dt, e) = ht[j = jt*16 + (lane>>4)*4+e][h*128 + dt*16 + (lane&15)]
__global__ __launch_bounds__(512) void k_htgemm(const float* __restrict__ h,
                                                const float* __restrict__ W,
                                                const float* __restrict__ a,
                                                const float* __restrict__ pos,
                                                _Float16* __restrict__ vfrag,
                                                _Float16* __restrict__ posfrag,
                                                float* __restrict__ src,
                                                float* __restrict__ tgt) {
  __shared__ float hs[16][128];
  __shared__ float red[8][16][2];
  const int jt = blockIdx.x;      // 16-node tile
  const int i0 = jt * 16;
  const int tid = threadIdx.x;
  for (int idx = tid; idx < 16 * 128; idx += 512)
    hs[idx >> 7][idx & 127] = h[(i0 + (idx >> 7)) * 128 + (idx & 127)];
  __syncthreads();
  const int c = tid;  // output column 0..511
  float acc[16];
#pragma unroll
  for (int r = 0; r < 16; ++r) acc[r] = 0.f;
  for (int k = 0; k < 128; ++k) {
    const float w = W[k * 512 + c];
#pragma unroll
    for (int r = 0; r < 16; ++r) acc[r] = fmaf(hs[r][k], w, acc[r]);
  }
  const int hc = c >> 7, d = c & 127;
  _Float16* vb = vfrag + ((size_t)(hc * 256 + jt) * 64) * 32 + (d >> 4) * 4;
#pragma unroll
  for (int rg = 0; rg < 4; ++rg) {
    h4 v;
    v.x = (_Float16)acc[rg * 4 + 0];
    v.y = (_Float16)acc[rg * 4 + 1];
    v.z = (_Float16)acc[rg * 4 + 2];
    v.w = (_Float16)acc[rg * 4 + 3];
    *(h4*)(vb + ((d & 15) + 16 * rg) * 32) = v;
  }
  const float av = a[hc * 256 + d];
  const float bvv = a[hc * 256 + 128 + d];
  float sv[16], tv[16];
#pragma unroll
  for (int r = 0; r < 16; ++r) { sv[r] = acc[r] * av; tv[r] = acc[r] * bvv; }
#pragma unroll
  for (int off = 32; off >= 1; off >>= 1) {
#pragma unroll
    for (int r = 0; r < 16; ++r) {
      sv[r] += __shfl_xor(sv[r], off, 64);
      tv[r] += __shfl_xor(tv[r], off, 64);
    }
  }
  const int w = tid >> 6;
  if ((tid & 63) == 0) {
#pragma unroll
    for (int r = 0; r < 16; ++r) { red[w][r][0] = sv[r]; red[w][r][1] = tv[r]; }
  }
  if (tid < 64) {
    const int rg = tid >> 4, n = tid & 15;
    h4 pv;
#pragma unroll
    for (int e = 0; e < 4; ++e) {
      const int j = i0 + rg * 4 + e;
      pv[e] = (_Float16)(n < 3 ? pos[j * 3 + n] : (n == 3 ? 1.f : 0.f));
    }
    *(h4*)(posfrag + (size_t)(jt * 64 + tid) * 4) = pv;
  }
  __syncthreads();
  if (tid < 128) {
    const int h2_ = tid >> 5, k = tid & 31, r = k >> 1, st = k & 1;
    const float vsum = (red[h2_ * 2][r][st] + red[h2_ * 2 + 1][r][st]) * LOG2E;
    (st ? tgt : src)[h2_ * NN + i0 + r] = vsum;
  }
}

// ---------------- K2: barrier-free fused attention (BI=32, r6 skeleton) ----------------
// block: 512 thr = 8 waves = 4 heads x 2 j-interleave; i-tile 32, j-range 1024.
// LDS: dist16 [32][1036] fp16 (masked dist * log2e), reused as f32 epilogue buffers.
#define JROW 1036
#define SMEM_BYTES 67584   // epilogue: 4*32*128*4 + 4*32*4*4 ; fill: 32*1036*2=66304

__global__ __launch_bounds__(512, 4) void k_attn(
    const _Float16* __restrict__ vfrag, const _Float16* __restrict__ posfrag,
    const int* __restrict__ adj, const float* __restrict__ pos,
    const float* __restrict__ src, const float* __restrict__ tgt,
    __hip_bfloat16* __restrict__ hp_part, __hip_bfloat16* __restrict__ ppart) {
  __shared__ __attribute__((aligned(16))) unsigned char smem[SMEM_BYTES];
  _Float16* dist16 = (_Float16*)smem;

  const int tid = threadIdx.x;
  const int bid = (int)blockIdx.x;
  const int ib = bid >> 2, jhb = bid & 3;
  const int i0 = ib * 32;
  const int jb = jhb * 1024;

  // ================= fill phase: masked dist (fp16, *log2e) =================
  {
    const int si = tid >> 4;             // row 0..31
    const int jc = (tid & 15) * 4;       // 4-j chunk; c-steps of 64
    const float pix = pos[(i0 + si) * 3 + 0];
    const float piy = pos[(i0 + si) * 3 + 1];
    const float piz = pos[(i0 + si) * 3 + 2];
    const int* adjp = adj + (size_t)(i0 + si) * NN + jb + jc;
    const float* posj = pos + (size_t)(jb + jc) * 3;
#pragma unroll
    for (int cc = 0; cc < 16; ++cc) {
      const int4 av = *(const int4*)(adjp + cc * 64);
      const float4 p0 = *(const float4*)(posj + cc * 192 + 0);
      const float4 p1 = *(const float4*)(posj + cc * 192 + 4);
      const float4 p2 = *(const float4*)(posj + cc * 192 + 8);
      float dx, dy, dz;
      h4 dd;
      dx = pix - p0.x; dy = piy - p0.y; dz = piz - p0.z;
      dd.x = (_Float16)(av.x > 0 ? sqrtf(dx * dx + dy * dy + dz * dz) * LOG2E : 4e4f);
      dx = pix - p0.w; dy = piy - p1.x; dz = piz - p1.y;
      dd.y = (_Float16)(av.y > 0 ? sqrtf(dx * dx + dy * dy + dz * dz) * LOG2E : 4e4f);
      dx = pix - p1.z; dy = piy - p1.w; dz = piz - p2.x;
      dd.z = (_Float16)(av.z > 0 ? sqrtf(dx * dx + dy * dy + dz * dz) * LOG2E : 4e4f);
      dx = pix - p2.y; dy = piy - p2.z; dz = piz - p2.w;
      dd.w = (_Float16)(av.w > 0 ? sqrtf(dx * dx + dy * dy + dz * dz) * LOG2E : 4e4f);
      *(h4*)(dist16 + si * JROW + jc + cc * 64) = dd;
    }
  }
  __syncthreads();

  // ================= main loop: barrier-free, 1-deep prefetch incl dd =================
  const int w = tid >> 6, lane = tid & 63;
  const int hh = w & 3, kp = w >> 2;
  const int il = lane & 15, kg = lane >> 4;

  const float srcv0 = src[hh * NN + i0 + il];
  const float srcv1 = src[hh * NN + i0 + 16 + il];

  f4 acc[2][8];
#pragma unroll
  for (int mp = 0; mp < 2; ++mp)
#pragma unroll
    for (int dt = 0; dt < 8; ++dt) acc[mp][dt] = (f4){0.f, 0.f, 0.f, 0.f};
  f4 pacc0 = (f4){0.f, 0.f, 0.f, 0.f};
  f4 pacc1 = (f4){0.f, 0.f, 0.f, 0.f};

  const int jt0 = (jb >> 4) + kp;
  const _Float16* vbase = vfrag + ((size_t)(hh * 256 + jt0) * 64 + lane) * 32;
  const _Float16* pbase = posfrag + (size_t)(jt0 * 64 + lane) * 4;
  const float* tbase = tgt + hh * NN + jb + kp * 16 + kg * 4;
  const _Float16* ddbase = dist16 + il * JROW + kp * 16 + kg * 4;

  // preload t=0
  h8 n01 = *(const h8*)(vbase);
  h8 n23 = *(const h8*)(vbase + 8);
  h8 n45 = *(const h8*)(vbase + 16);
  h8 n67 = *(const h8*)(vbase + 24);
  h4 npf = *(const h4*)(pbase);
  float4 ntt = *(const float4*)(tbase);
  h4 ndd0 = *(const h4*)(ddbase);
  h4 ndd1 = *(const h4*)(ddbase + 16 * JROW);

#pragma unroll 2
  for (int t = 0; t < 32; ++t) {
    const h8 v01 = n01, v23 = n23, v45 = n45, v67 = n67;
    const h4 pf = npf;
    const float4 tt = ntt;
    const h4 dd0 = ndd0, dd1 = ndd1;
    if (t < 31) {
      const _Float16* vfn = vbase + (size_t)(t + 1) * 4096;
      n01 = *(const h8*)(vfn);
      n23 = *(const h8*)(vfn + 8);
      n45 = *(const h8*)(vfn + 16);
      n67 = *(const h8*)(vfn + 24);
      npf = *(const h4*)(pbase + (t + 1) * 512);
      ntt = *(const float4*)(tbase + (t + 1) * 32);
      ndd0 = *(const h4*)(ddbase + (t + 1) * 32);
      ndd1 = *(const h4*)(ddbase + 16 * JROW + (t + 1) * 32);
    }
    // af chains (logits already *log2e -> raw exp2)
    float e0 = (srcv0 + tt.x) - (float)dd0.x;
    float e1 = (srcv0 + tt.y) - (float)dd0.y;
    float e2 = (srcv0 + tt.z) - (float)dd0.z;
    float e3 = (srcv0 + tt.w) - (float)dd0.w;
    e0 = fmaxf(e0, 0.2f * e0); e1 = fmaxf(e1, 0.2f * e1);
    e2 = fmaxf(e2, 0.2f * e2); e3 = fmaxf(e3, 0.2f * e3);
    const h2 lo0 = cvt2(EXP2(e0), EXP2(e1));
    const h2 hi0 = cvt2(EXP2(e2), EXP2(e3));
    const h4 af0 = __builtin_shufflevector(lo0, hi0, 0, 1, 2, 3);
    float f0 = (srcv1 + tt.x) - (float)dd1.x;
    float f1 = (srcv1 + tt.y) - (float)dd1.y;
    float f2 = (srcv1 + tt.z) - (float)dd1.z;
    float f3 = (srcv1 + tt.w) - (float)dd1.w;
    f0 = fmaxf(f0, 0.2f * f0); f1 = fmaxf(f1, 0.2f * f1);
    f2 = fmaxf(f2, 0.2f * f2); f3 = fmaxf(f3, 0.2f * f3);
    const h2 lo1 = cvt2(EXP2(f0), EXP2(f1));
    const h2 hi1 = cvt2(EXP2(f2), EXP2(f3));
    const h4 af1 = __builtin_shufflevector(lo1, hi1, 0, 1, 2, 3);
    h4 vfj[8];
    vfj[0] = __builtin_shufflevector(v01, v01, 0, 1, 2, 3);
    vfj[1] = __builtin_shufflevector(v01, v01, 4, 5, 6, 7);
    vfj[2] = __builtin_shufflevector(v23, v23, 0, 1, 2, 3);
    vfj[3] = __builtin_shufflevector(v23, v23, 4, 5, 6, 7);
    vfj[4] = __builtin_shufflevector(v45, v45, 0, 1, 2, 3);
    vfj[5] = __builtin_shufflevector(v45, v45, 4, 5, 6, 7);
    vfj[6] = __builtin_shufflevector(v67, v67, 0, 1, 2, 3);
    vfj[7] = __builtin_shufflevector(v67, v67, 4, 5, 6, 7);
    __builtin_amdgcn_s_setprio(1);
#pragma unroll
    for (int dt = 0; dt < 8; ++dt)
      acc[0][dt] = __builtin_amdgcn_mfma_f32_16x16x16f16(af0, vfj[dt], acc[0][dt], 0, 0, 0);
    pacc0 = __builtin_amdgcn_mfma_f32_16x16x16f16(af0, pf, pacc0, 0, 0, 0);
#pragma unroll
    for (int dt = 0; dt < 8; ++dt)
      acc[1][dt] = __builtin_amdgcn_mfma_f32_16x16x16f16(af1, vfj[dt], acc[1][dt], 0, 0, 0);
    pacc1 = __builtin_amdgcn_mfma_f32_16x16x16f16(af1, pf, pacc1, 0, 0, 0);
    __builtin_amdgcn_s_setprio(0);
  }

  // ================= epilogue: sum kp halves, write bf16 partials =================
  __syncthreads();
  float* eps = (float*)smem;                  // [4 h][32 i][128 d]
  float* pacc_s = (float*)(smem + 65536);     // [4 h][32 i][4]
  if (kp == 1) {
#pragma unroll
    for (int mp = 0; mp < 2; ++mp)
#pragma unroll
      for (int dt = 0; dt < 8; ++dt)
#pragma unroll
        for (int r = 0; r < 4; ++r)
          eps[(hh * 32 + mp * 16 + kg * 4 + r) * 128 + dt * 16 + il] = acc[mp][dt][r];
    if (il < 4) {
#pragma unroll
      for (int r = 0; r < 4; ++r) {
        pacc_s[(hh * 32 + kg * 4 + r) * 4 + il] = pacc0[r];
        pacc_s[(hh * 32 + 16 + kg * 4 + r) * 4 + il] = pacc1[r];
      }
    }
  }
  __syncthreads();
  if (kp == 0) {
    __hip_bfloat16* hpb = hp_part + ((size_t)(jhb * 4 + hh) * NN + i0) * 128;
#pragma unroll
    for (int mp = 0; mp < 2; ++mp)
#pragma unroll
      for (int dt = 0; dt < 8; ++dt)
#pragma unroll
        for (int r = 0; r < 4; ++r) {
          const int ii = mp * 16 + kg * 4 + r;
          const float s = (mp == 0 ? acc[0][dt][r] : acc[1][dt][r]) +
                          eps[(hh * 32 + ii) * 128 + dt * 16 + il];
          hpb[(size_t)ii * 128 + dt * 16 + il] = __float2bfloat16(s);
        }
    if (il < 4) {
#pragma unroll
      for (int r = 0; r < 4; ++r) {
        const float s0 = pacc0[r] + pacc_s[(hh * 32 + kg * 4 + r) * 4 + il];
        ppart[((size_t)(jhb * 4 + hh) * NN + i0 + kg * 4 + r) * 4 + il] =
            __float2bfloat16(s0);
        const float s1 = pacc1[r] + pacc_s[(hh * 32 + 16 + kg * 4 + r) * 4 + il];
        ppart[((size_t)(jhb * 4 + hh) * NN + i0 + 16 + kg * 4 + r) * 4 + il] =
            __float2bfloat16(s1);
      }
    }
  }
}

// ---------------- K3: reduce partials + LayerNorm + residual + pos ----------------
__global__ __launch_bounds__(128) void k_finish(
    const __hip_bfloat16* __restrict__ hp_part,
    const __hip_bfloat16* __restrict__ ppart, const float* __restrict__ hin,
    const float* __restrict__ pos, const float* __restrict__ gamma,
    const float* __restrict__ beta, float* __restrict__ hout,
    float* __restrict__ out_pos) {
  __shared__ float red[2][2];
  const int i = blockIdx.x, d = threadIdx.x;
  float Li[4];
  float v = 0.f;
#pragma unroll
  for (int hx = 0; hx < 4; ++hx) {
    float L = 0.f, hv = 0.f;
#pragma unroll
    for (int jh = 0; jh < 4; ++jh) {
      L += __bfloat162float(ppart[((size_t)(jh * 4 + hx) * NN + i) * 4 + 3]);
      hv += __bfloat162float(hp_part[((size_t)(jh * 4 + hx) * NN + i) * 128 + d]);
    }
    Li[hx] = 1.f / L;
    v += hv * Li[hx];
  }
  v *= 0.25f;
  float s = v, sq = v * v;
#pragma unroll
  for (int off = 32; off >= 1; off >>= 1) {
    s += __shfl_xor(s, off, 64);
    sq += __shfl_xor(sq, off, 64);
  }
  const int wv = d >> 6;
  if ((d & 63) == 0) { red[wv][0] = s; red[wv][1] = sq; }
  __syncthreads();
  s = red[0][0] + red[1][0];
  sq = red[0][1] + red[1][1];
  const float mu = s * (1.f / 128.f);
  const float var = sq * (1.f / 128.f) - mu * mu;
  const float hn = (v - mu) * rsqrtf(var + 1e-5f) * gamma[d] + beta[d];
  hout[i * 128 + d] = hin[i * 128 + d] + hn;
  if (d < 3) {
    float sp = 0.f;
#pragma unroll
    for (int hx = 0; hx < 4; ++hx) {
      float pv = 0.f;
#pragma unroll
      for (int jh = 0; jh < 4; ++jh)
        pv += __bfloat162float(ppart[((size_t)(jh * 4 + hx) * NN + i) * 4 + d]);
      sp += pv * Li[hx];
    }
    out_pos[i * 3 + d] = 2.f * pos[i * 3 + d] - 0.25f * sp;
  }
}

extern "C" void kernel_launch(void* const* d_in, const int* in_sizes, int n_in,
                              void* d_out, int out_size, void* d_ws, size_t ws_size,
                              hipStream_t stream) {
  const float* h     = (const float*)d_in[0];
  const int*   adj   = (const int*)d_in[1];
  const float* pos   = (const float*)d_in[2];
  const float* W     = (const float*)d_in[3];
  const float* a     = (const float*)d_in[4];
  const float* gamma = (const float*)d_in[5];
  const float* beta  = (const float*)d_in[6];
  float* out = (float*)d_out;

  unsigned char* ws = (unsigned char*)d_ws;
  _Float16* vfrag   = (_Float16*)ws;                         // 4,194,304 B
  _Float16* posfrag = (_Float16*)(ws + 4194304);             // 131,072 B
  float* src        = (float*)(ws + 4194304 + 131072);       // 65,536 B
  float* tgt        = (float*)(ws + 4194304 + 131072 + 65536);
  __hip_bfloat16* hp_part =
      (__hip_bfloat16*)(ws + 4194304 + 131072 + 131072);     // 16,777,216 B
  __hip_bfloat16* ppart =
      (__hip_bfloat16*)(ws + 4194304 + 131072 + 131072 + 16777216);  // 524,288 B

  k_htgemm<<<NN / 16, 512, 0, stream>>>(h, W, a, pos, vfrag, posfrag, src, tgt);
  k_attn<<<(NN / 32) * 4, 512, 0, stream>>>(vfrag, posfrag, adj, pos, src, tgt,
                                            hp_part, ppart);
  k_finish<<<NN, 128, 0, stream>>>(hp_part, ppart, h, pos, gamma, beta, out,
                                   out + NN * 128);
}

// Round 11
// 95.008 us; speedup vs baseline: 1.4431x; 1.4431x over previous
//
#include <hip/hip_runtime.h>
#include <hip/hip_bf16.h>
#include <hip/hip_fp16.h>
#include <math.h>

#define NN 4096
#define HH 4
#define LOG2E 1.44269504f

typedef _Float16 h2 __attribute__((ext_vector_type(2)));
typedef _Float16 h4 __attribute__((ext_vector_type(4)));
typedef _Float16 h8 __attribute__((ext_vector_type(8)));
typedef unsigned short us4 __attribute__((ext_vector_type(4)));
typedef float f4 __attribute__((ext_vector_type(4)));

static __device__ __forceinline__ _Float16 hx2(_Float16 v) {
  return __builtin_bit_cast(_Float16, hexp2(__builtin_bit_cast(__half, v)));
}
static __device__ __forceinline__ h4 habs4(h4 x) {
  us4 u = __builtin_bit_cast(us4, x);
  const us4 m = {0x7FFF, 0x7FFF, 0x7FFF, 0x7FFF};
  u = u & m;
  return __builtin_bit_cast(h4, u);
}

// ---------------- K1: ht GEMM -> vfrag + posfrag + src16/tgt16 (prescaled fp16) ----------------
// vfrag element (h, jt, lane, dt, e) = ht[j = jt*16 + (lane>>4)*4+e][h*128 + dt*16 + (lane&15)]
__global__ __launch_bounds__(512) void k_htgemm(const float* __restrict__ h,
                                                const float* __restrict__ W,
                                                const float* __restrict__ a,
                                                const float* __restrict__ pos,
                                                _Float16* __restrict__ vfrag,
                                                _Float16* __restrict__ posfrag,
                                                _Float16* __restrict__ src16,
                                                _Float16* __restrict__ tgt16) {
  __shared__ float hs[16][128];
  __shared__ float red[8][16][2];
  const int jt = blockIdx.x;      // 16-node tile
  const int i0 = jt * 16;
  const int tid = threadIdx.x;
  for (int idx = tid; idx < 16 * 128; idx += 512)
    hs[idx >> 7][idx & 127] = h[(i0 + (idx >> 7)) * 128 + (idx & 127)];
  __syncthreads();
  const int c = tid;  // output column 0..511
  float acc[16];
#pragma unroll
  for (int r = 0; r < 16; ++r) acc[r] = 0.f;
  for (int k = 0; k < 128; ++k) {
    const float w = W[k * 512 + c];
#pragma unroll
    for (int r = 0; r < 16; ++r) acc[r] = fmaf(hs[r][k], w, acc[r]);
  }
  const int hc = c >> 7, d = c & 127;
  _Float16* vb = vfrag + ((size_t)(hc * 256 + jt) * 64) * 32 + (d >> 4) * 4;
#pragma unroll
  for (int rg = 0; rg < 4; ++rg) {
    h4 v;
    v.x = (_Float16)acc[rg * 4 + 0];
    v.y = (_Float16)acc[rg * 4 + 1];
    v.z = (_Float16)acc[rg * 4 + 2];
    v.w = (_Float16)acc[rg * 4 + 3];
    *(h4*)(vb + ((d & 15) + 16 * rg) * 32) = v;
  }
  const float av = a[hc * 256 + d];
  const float bvv = a[hc * 256 + 128 + d];
  float sv[16], tv[16];
#pragma unroll
  for (int r = 0; r < 16; ++r) { sv[r] = acc[r] * av; tv[r] = acc[r] * bvv; }
#pragma unroll
  for (int off = 32; off >= 1; off >>= 1) {
#pragma unroll
    for (int r = 0; r < 16; ++r) {
      sv[r] += __shfl_xor(sv[r], off, 64);
      tv[r] += __shfl_xor(tv[r], off, 64);
    }
  }
  const int w = tid >> 6;
  if ((tid & 63) == 0) {
#pragma unroll
    for (int r = 0; r < 16; ++r) { red[w][r][0] = sv[r]; red[w][r][1] = tv[r]; }
  }
  if (tid < 64) {
    const int rg = tid >> 4, n = tid & 15;
    h4 pv;
#pragma unroll
    for (int e = 0; e < 4; ++e) {
      const int j = i0 + rg * 4 + e;
      pv[e] = (_Float16)(n < 3 ? pos[j * 3 + n] : (n == 3 ? 1.f : 0.f));
    }
    *(h4*)(posfrag + (size_t)(jt * 64 + tid) * 4) = pv;
  }
  __syncthreads();
  if (tid < 128) {
    const int h2_ = tid >> 5, k = tid & 31, r = k >> 1, st = k & 1;
    const float vsum = (red[h2_ * 2][r][st] + red[h2_ * 2 + 1][r][st]) * LOG2E;
    (st ? tgt16 : src16)[h2_ * NN + i0 + r] = (_Float16)vsum;
  }
}

// ---------------- K2: barrier-free fused attention (r6 skeleton, fp16 logit chain) ----------------
// block: 512 thr = 8 waves = 4 heads x 2 j-interleave; i-tile 32, j-range 1024.
// LDS: dist16 [32][1036] fp16 (masked dist * log2e), reused as f32 epilogue buffers.
#define JROW 1036
#define SMEM_BYTES 67584   // epilogue: 4*32*128*4 + 4*32*4*4 ; fill: 32*1036*2=66304

__global__ __launch_bounds__(512, 4) void k_attn(
    const _Float16* __restrict__ vfrag, const _Float16* __restrict__ posfrag,
    const int* __restrict__ adj, const float* __restrict__ pos,
    const _Float16* __restrict__ src16, const _Float16* __restrict__ tgt16,
    __hip_bfloat16* __restrict__ hp_part, __hip_bfloat16* __restrict__ ppart) {
  __shared__ __attribute__((aligned(16))) unsigned char smem[SMEM_BYTES];
  _Float16* dist16 = (_Float16*)smem;

  const int tid = threadIdx.x;
  const int bid = (int)blockIdx.x;
  const int ib = bid >> 2, jhb = bid & 3;
  const int i0 = ib * 32;
  const int jb = jhb * 1024;

  // ================= fill phase: masked dist (fp16, *log2e) =================
  {
    const int si = tid >> 4;             // row 0..31
    const int jc = (tid & 15) * 4;       // 4-j chunk; c-steps of 64
    const float pix = pos[(i0 + si) * 3 + 0];
    const float piy = pos[(i0 + si) * 3 + 1];
    const float piz = pos[(i0 + si) * 3 + 2];
    const int* adjp = adj + (size_t)(i0 + si) * NN + jb + jc;
    const float* posj = pos + (size_t)(jb + jc) * 3;
#pragma unroll
    for (int cc = 0; cc < 16; ++cc) {
      const int4 av = *(const int4*)(adjp + cc * 64);
      const float4 p0 = *(const float4*)(posj + cc * 192 + 0);
      const float4 p1 = *(const float4*)(posj + cc * 192 + 4);
      const float4 p2 = *(const float4*)(posj + cc * 192 + 8);
      float dx, dy, dz;
      h4 dd;
      dx = pix - p0.x; dy = piy - p0.y; dz = piz - p0.z;
      dd.x = (_Float16)(av.x > 0 ? sqrtf(dx * dx + dy * dy + dz * dz) * LOG2E : 4e4f);
      dx = pix - p0.w; dy = piy - p1.x; dz = piz - p1.y;
      dd.y = (_Float16)(av.y > 0 ? sqrtf(dx * dx + dy * dy + dz * dz) * LOG2E : 4e4f);
      dx = pix - p1.z; dy = piy - p1.w; dz = piz - p2.x;
      dd.z = (_Float16)(av.z > 0 ? sqrtf(dx * dx + dy * dy + dz * dz) * LOG2E : 4e4f);
      dx = pix - p2.y; dy = piy - p2.z; dz = piz - p2.w;
      dd.w = (_Float16)(av.w > 0 ? sqrtf(dx * dx + dy * dy + dz * dz) * LOG2E : 4e4f);
      *(h4*)(dist16 + si * JROW + jc + cc * 64) = dd;
    }
  }
  __syncthreads();

  // ================= main loop: r6 structure, fp16 packed chain =================
  const int w = tid >> 6, lane = tid & 63;
  const int hh = w & 3, kp = w >> 2;
  const int il = lane & 15, kg = lane >> 4;

  const _Float16 s0 = src16[hh * NN + i0 + il];
  const _Float16 s1 = src16[hh * NN + i0 + 16 + il];
  const h4 sv0 = {s0, s0, s0, s0};
  const h4 sv1 = {s1, s1, s1, s1};
  const _Float16 c06 = (_Float16)0.6f, c04 = (_Float16)0.4f;
  const h4 C06 = {c06, c06, c06, c06};
  const h4 C04 = {c04, c04, c04, c04};

  f4 acc[2][8];
#pragma unroll
  for (int mp = 0; mp < 2; ++mp)
#pragma unroll
    for (int dt = 0; dt < 8; ++dt) acc[mp][dt] = (f4){0.f, 0.f, 0.f, 0.f};
  f4 pacc0 = (f4){0.f, 0.f, 0.f, 0.f};
  f4 pacc1 = (f4){0.f, 0.f, 0.f, 0.f};

  const int jt0 = (jb >> 4) + kp;
  const _Float16* vbase = vfrag + ((size_t)(hh * 256) * 64 + lane) * 32;
  const _Float16* pbase = posfrag + (size_t)lane * 4;
  const _Float16* tbase = tgt16 + hh * NN + jb + kp * 16 + kg * 4;
  const _Float16* ddbase = dist16 + il * JROW + kp * 16 + kg * 4;

#pragma unroll 2
  for (int t = 0; t < 32; ++t) {
    const int jt = jt0 + 2 * t;
    const _Float16* vf = vbase + (size_t)jt * 2048;
    const h8 v01 = *(const h8*)(vf);
    const h8 v23 = *(const h8*)(vf + 8);
    const h8 v45 = *(const h8*)(vf + 16);
    const h8 v67 = *(const h8*)(vf + 24);
    const h4 pf = *(const h4*)(pbase + (size_t)jt * 256);
    const h4 tt = *(const h4*)(tbase + 2 * t * 16);
    const h4 dd0 = *(const h4*)(ddbase + t * 32);
    const h4 dd1 = *(const h4*)(ddbase + 16 * JROW + t * 32);
    // packed fp16 logit chain: x = (sv+tt)-dd ; leaky = 0.6x + 0.4|x| ; af = exp2(leaky)
    h4 x0 = (sv0 + tt) - dd0;
    h4 x1 = (sv1 + tt) - dd1;
    x0 = x0 * C06 + habs4(x0) * C04;
    x1 = x1 * C06 + habs4(x1) * C04;
    h4 af0, af1;
    af0.x = hx2(x0.x); af0.y = hx2(x0.y); af0.z = hx2(x0.z); af0.w = hx2(x0.w);
    af1.x = hx2(x1.x); af1.y = hx2(x1.y); af1.z = hx2(x1.z); af1.w = hx2(x1.w);
    h4 vfj[8];
    vfj[0] = __builtin_shufflevector(v01, v01, 0, 1, 2, 3);
    vfj[1] = __builtin_shufflevector(v01, v01, 4, 5, 6, 7);
    vfj[2] = __builtin_shufflevector(v23, v23, 0, 1, 2, 3);
    vfj[3] = __builtin_shufflevector(v23, v23, 4, 5, 6, 7);
    vfj[4] = __builtin_shufflevector(v45, v45, 0, 1, 2, 3);
    vfj[5] = __builtin_shufflevector(v45, v45, 4, 5, 6, 7);
    vfj[6] = __builtin_shufflevector(v67, v67, 0, 1, 2, 3);
    vfj[7] = __builtin_shufflevector(v67, v67, 4, 5, 6, 7);
#pragma unroll
    for (int dt = 0; dt < 8; ++dt)
      acc[0][dt] = __builtin_amdgcn_mfma_f32_16x16x16f16(af0, vfj[dt], acc[0][dt], 0, 0, 0);
    pacc0 = __builtin_amdgcn_mfma_f32_16x16x16f16(af0, pf, pacc0, 0, 0, 0);
#pragma unroll
    for (int dt = 0; dt < 8; ++dt)
      acc[1][dt] = __builtin_amdgcn_mfma_f32_16x16x16f16(af1, vfj[dt], acc[1][dt], 0, 0, 0);
    pacc1 = __builtin_amdgcn_mfma_f32_16x16x16f16(af1, pf, pacc1, 0, 0, 0);
  }

  // ================= epilogue: sum kp halves, write bf16 partials =================
  __syncthreads();
  float* eps = (float*)smem;                  // [4 h][32 i][128 d]
  float* pacc_s = (float*)(smem + 65536);     // [4 h][32 i][4]
  if (kp == 1) {
#pragma unroll
    for (int mp = 0; mp < 2; ++mp)
#pragma unroll
      for (int dt = 0; dt < 8; ++dt)
#pragma unroll
        for (int r = 0; r < 4; ++r)
          eps[(hh * 32 + mp * 16 + kg * 4 + r) * 128 + dt * 16 + il] = acc[mp][dt][r];
    if (il < 4) {
#pragma unroll
      for (int r = 0; r < 4; ++r) {
        pacc_s[(hh * 32 + kg * 4 + r) * 4 + il] = pacc0[r];
        pacc_s[(hh * 32 + 16 + kg * 4 + r) * 4 + il] = pacc1[r];
      }
    }
  }
  __syncthreads();
  if (kp == 0) {
    __hip_bfloat16* hpb = hp_part + ((size_t)(jhb * 4 + hh) * NN + i0) * 128;
#pragma unroll
    for (int mp = 0; mp < 2; ++mp)
#pragma unroll
      for (int dt = 0; dt < 8; ++dt)
#pragma unroll
        for (int r = 0; r < 4; ++r) {
          const int ii = mp * 16 + kg * 4 + r;
          const float s = (mp == 0 ? acc[0][dt][r] : acc[1][dt][r]) +
                          eps[(hh * 32 + ii) * 128 + dt * 16 + il];
          hpb[(size_t)ii * 128 + dt * 16 + il] = __float2bfloat16(s);
        }
    if (il < 4) {
#pragma unroll
      for (int r = 0; r < 4; ++r) {
        const float s0w = pacc0[r] + pacc_s[(hh * 32 + kg * 4 + r) * 4 + il];
        ppart[((size_t)(jhb * 4 + hh) * NN + i0 + kg * 4 + r) * 4 + il] =
            __float2bfloat16(s0w);
        const float s1w = pacc1[r] + pacc_s[(hh * 32 + 16 + kg * 4 + r) * 4 + il];
        ppart[((size_t)(jhb * 4 + hh) * NN + i0 + 16 + kg * 4 + r) * 4 + il] =
            __float2bfloat16(s1w);
      }
    }
  }
}

// ---------------- K3: reduce partials + LayerNorm + residual + pos ----------------
__global__ __launch_bounds__(128) void k_finish(
    const __hip_bfloat16* __restrict__ hp_part,
    const __hip_bfloat16* __restrict__ ppart, const float* __restrict__ hin,
    const float* __restrict__ pos, const float* __restrict__ gamma,
    const float* __restrict__ beta, float* __restrict__ hout,
    float* __restrict__ out_pos) {
  __shared__ float red[2][2];
  const int i = blockIdx.x, d = threadIdx.x;
  float Li[4];
  float v = 0.f;
#pragma unroll
  for (int hx = 0; hx < 4; ++hx) {
    float L = 0.f, hv = 0.f;
#pragma unroll
    for (int jh = 0; jh < 4; ++jh) {
      L += __bfloat162float(ppart[((size_t)(jh * 4 + hx) * NN + i) * 4 + 3]);
      hv += __bfloat162float(hp_part[((size_t)(jh * 4 + hx) * NN + i) * 128 + d]);
    }
    Li[hx] = 1.f / L;
    v += hv * Li[hx];
  }
  v *= 0.25f;
  float s = v, sq = v * v;
#pragma unroll
  for (int off = 32; off >= 1; off >>= 1) {
    s += __shfl_xor(s, off, 64);
    sq += __shfl_xor(sq, off, 64);
  }
  const int wv = d >> 6;
  if ((d & 63) == 0) { red[wv][0] = s; red[wv][1] = sq; }
  __syncthreads();
  s = red[0][0] + red[1][0];
  sq = red[0][1] + red[1][1];
  const float mu = s * (1.f / 128.f);
  const float var = sq * (1.f / 128.f) - mu * mu;
  const float hn = (v - mu) * rsqrtf(var + 1e-5f) * gamma[d] + beta[d];
  hout[i * 128 + d] = hin[i * 128 + d] + hn;
  if (d < 3) {
    float sp = 0.f;
#pragma unroll
    for (int hx = 0; hx < 4; ++hx) {
      float pv = 0.f;
#pragma unroll
      for (int jh = 0; jh < 4; ++jh)
        pv += __bfloat162float(ppart[((size_t)(jh * 4 + hx) * NN + i) * 4 + d]);
      sp += pv * Li[hx];
    }
    out_pos[i * 3 + d] = 2.f * pos[i * 3 + d] - 0.25f * sp;
  }
}

extern "C" void kernel_launch(void* const* d_in, const int* in_sizes, int n_in,
                              void* d_out, int out_size, void* d_ws, size_t ws_size,
                              hipStream_t stream) {
  const float* h     = (const float*)d_in[0];
  const int*   adj   = (const int*)d_in[1];
  const float* pos   = (const float*)d_in[2];
  const float* W     = (const float*)d_in[3];
  const float* a     = (const float*)d_in[4];
  const float* gamma = (const float*)d_in[5];
  const float* beta  = (const float*)d_in[6];
  float* out = (float*)d_out;

  unsigned char* ws = (unsigned char*)d_ws;
  _Float16* vfrag   = (_Float16*)ws;                         // 4,194,304 B
  _Float16* posfrag = (_Float16*)(ws + 4194304);             // 131,072 B
  _Float16* src16   = (_Float16*)(ws + 4194304 + 131072);    // 32,768 B
  _Float16* tgt16   = (_Float16*)(ws + 4194304 + 131072 + 65536);
  __hip_bfloat16* hp_part =
      (__hip_bfloat16*)(ws + 4194304 + 131072 + 131072);     // 16,777,216 B
  __hip_bfloat16* ppart =
      (__hip_bfloat16*)(ws + 4194304 + 131072 + 131072 + 16777216);  // 524,288 B

  k_htgemm<<<NN / 16, 512, 0, stream>>>(h, W, a, pos, vfrag, posfrag, src16, tgt16);
  k_attn<<<(NN / 32) * 4, 512, 0, stream>>>(vfrag, posfrag, adj, pos, src16, tgt16,
                                            hp_part, ppart);
  k_finish<<<NN, 128, 0, stream>>>(hp_part, ppart, h, pos, gamma, beta, out,
                                   out + NN * 128);
}